// Round 8
// baseline (790.356 us; speedup 1.0000x reference)
//
#include <hip/hip_runtime.h>

// Problem constants
#define B_N 4096
#define T_N 512
// Output layout (floats): final (B,T,2) | fwd_out (B,2) | noise (B,T,1)
#define FWD_OFF   (B_N * T_N * 2)        // 4194304
#define NOISE_OFF (FWD_OFF + B_N * 2)    // 4202496

#define S_SIG  (-1.4426950408889634f)   // -log2(e)
#define S_TANH (-2.8853900817779268f)   // -2*log2(e)

__device__ __forceinline__ float sig_acc(float a) {
    return __builtin_amdgcn_rcpf(1.0f + __builtin_amdgcn_exp2f(a));
}
__device__ __forceinline__ float tanh_acc(float a) {
    return fmaf(2.0f, __builtin_amdgcn_rcpf(1.0f + __builtin_amdgcn_exp2f(a)), -1.0f);
}
__device__ __forceinline__ float tanh_nat(float v) { return tanh_acc(v * S_TANH); }
__device__ __forceinline__ float act_ab(float a, float A, float Bc) {
    float r = __builtin_amdgcn_rcpf(1.0f + __builtin_amdgcn_exp2f(a));
    return fmaf(A, r, Bc);
}
// ds_bpermute: byte address selects source lane within the wave
__device__ __forceinline__ float bperm(int byteaddr, float v) {
    return __int_as_float(__builtin_amdgcn_ds_bpermute(byteaddr, __float_as_int(v)));
}

// One batch element per 64-lane wave; one gate-row per lane.
// Grid = 4096 waves = 1024 blocks x 256 = 4 waves/SIMD chip-wide.
// waves_per_eu(4,4): allocator plans for exactly 4 waves/EU (128-VGPR budget);
// per-lane live set is ~95 regs -> residency is the cheap option (finally).
__global__ __launch_bounds__(256) __attribute__((amdgpu_waves_per_eu(4, 4)))
void fused_kernel(
    const float* __restrict__ x,
    const float* __restrict__ eWih0, const float* __restrict__ eWhh0,
    const float* __restrict__ ebih0, const float* __restrict__ ebhh0,
    const float* __restrict__ eWih1, const float* __restrict__ eWhh1,
    const float* __restrict__ ebih1, const float* __restrict__ ebhh1,
    const float* __restrict__ dWih0, const float* __restrict__ dWhh0,
    const float* __restrict__ dbih0, const float* __restrict__ dbhh0,
    const float* __restrict__ dWih1, const float* __restrict__ dWhh1,
    const float* __restrict__ dbih1, const float* __restrict__ dbhh1,
    const float* __restrict__ fcW, const float* __restrict__ fcb,
    const float* __restrict__ outW, const float* __restrict__ outb,
    float* __restrict__ out)
{
    const int tid = blockIdx.x * 256 + threadIdx.x;
    const int b   = tid >> 6;             // one element per wave
    const int wl  = threadIdx.x & 63;     // lane in wave

    // =================== ENCODER (16-lane groups, 4 redundant copies) ===================
    const int r16 = wl & 15;
    const int u4  = r16 & 3;
    const int kk  = r16 >> 2;
    const float esc = (kk == 2) ? S_TANH : S_SIG;
    const float eAk = (kk == 2) ? 2.0f : 1.0f;
    const float eBk = (kk == 2) ? -1.0f : 0.0f;

    const int gb  = (wl & ~15) << 2;              // 16-group base byte addr
    const int ea_i = gb + (u4 << 2);
    const int ea_f = gb + ((u4 + 4) << 2);
    const int ea_g = gb + ((u4 + 8) << 2);
    const int ea_o = gb + ((u4 + 12) << 2);

    float h0v[4] = {0.f, 0.f, 0.f, 0.f};
    float h1v[4] = {0.f, 0.f, 0.f, 0.f};
    float c0 = 0.f, c1 = 0.f;
    float fw0, fw1;

    {
        float ew0  = eWih0[r16] * esc;
        float eb0c = (ebih0[r16] + ebhh0[r16]) * esc;
        float eb1c = (ebih1[r16] + ebhh1[r16]) * esc;
        float ewh0[4], ewi1[4], ewh1[4];
#pragma unroll
        for (int j = 0; j < 4; ++j) {
            ewh0[j] = eWhh0[r16 * 4 + j] * esc;
            ewi1[j] = eWih1[r16 * 4 + j] * esc;
            ewh1[j] = eWhh1[r16 * 4 + j] * esc;
        }

        const float4* __restrict__ xq4 = (const float4*)(x + (long)b * T_N);
        float4 xq = xq4[0];

        auto estep = [&](float xc) {
            // L1 partial from previous h1 (independent of L0 chain)
            float p = eb1c;
#pragma unroll
            for (int j = 0; j < 4; ++j) p = fmaf(ewh1[j], h1v[j], p);

            float g = fmaf(ew0, xc, eb0c);
#pragma unroll
            for (int j = 0; j < 4; ++j) g = fmaf(ewh0[j], h0v[j], g);
            float gate = act_ab(g, eAk, eBk);
            float iv = bperm(ea_i, gate);
            float fv = bperm(ea_f, gate);
            float gv = bperm(ea_g, gate);
            float ov = bperm(ea_o, gate);
            c0 = fmaf(fv, c0, iv * gv);            // unit-u4 state, all lanes
            float h0u = ov * tanh_nat(c0);
#pragma unroll
            for (int j = 0; j < 4; ++j) h0v[j] = bperm(gb + (j << 2), h0u);

            float q = ewi1[0] * h0v[0];
#pragma unroll
            for (int j = 1; j < 4; ++j) q = fmaf(ewi1[j], h0v[j], q);
            float gate1 = act_ab(p + q, eAk, eBk);
            iv = bperm(ea_i, gate1);
            fv = bperm(ea_f, gate1);
            gv = bperm(ea_g, gate1);
            ov = bperm(ea_o, gate1);
            c1 = fmaf(fv, c1, iv * gv);
            float h1u = ov * tanh_nat(c1);
#pragma unroll
            for (int j = 0; j < 4; ++j) h1v[j] = bperm(gb + (j << 2), h1u);
        };

        for (int tb = 0; tb < T_N / 4; ++tb) {
            float4 xn = (tb + 1 < T_N / 4) ? xq4[tb + 1] : xq;  // prefetch
            estep(xq.x); estep(xq.y); estep(xq.z); estep(xq.w);
            xq = xn;
        }

        fw0 = fcb[0]; fw1 = fcb[1];
#pragma unroll
        for (int j = 0; j < 4; ++j) {
            fw0 = fmaf(fcW[j], h1v[j], fw0);
            fw1 = fmaf(fcW[4 + j], h1v[j], fw1);
        }
        if (wl == 0) {
            out[FWD_OFF + b * 2 + 0] = fw0;
            out[FWD_OFF + b * 2 + 1] = fw1;
        }
    }

    // =================== DECODER: one gate-row per lane (H=10) ===================
    // Rows r = k*10+u, k in {i,f,g,o}, u = unit. Lanes 0..39 own rows 0..39;
    // lanes 40..63 shadow rows 0..23 (valid duplicates, needed for noise staging).
    const int row = (wl < 40) ? wl : (wl - 40);
    const int k   = (row >= 30) ? 3 : (row >= 20) ? 2 : (row >= 10) ? 1 : 0;
    const int u   = row - k * 10;
    const float scl = (k == 2) ? S_TANH : S_SIG;
    const float A1  = (k == 2) ? 2.0f : 1.0f;
    const float B1  = (k == 2) ? -1.0f : 0.0f;

    float wih0 = dWih0[row] * scl;
    float bb0  = (dbih0[row] + dbhh0[row]) * scl;
    float bb1  = (dbih1[row] + dbhh1[row]) * scl;
    float whh0r[10], wih1r[10], whh1r[10], outw[10];
#pragma unroll
    for (int j = 0; j < 10; ++j) {
        whh0r[j] = dWhh0[row * 10 + j] * scl;
        wih1r[j] = dWih1[row * 10 + j] * scl;
        whh1r[j] = dWhh1[row * 10 + j] * scl;
        outw[j]  = outW[j];
    }
    const float outb0 = outb[0];

    // Wave-wide bpermute byte addresses (loop-invariant)
    const int a_i = u << 2;
    const int a_f = (10 + u) << 2;
    const int a_g = (20 + u) << 2;
    const int a_o = (30 + u) << 2;

    // State handoff: lane u (u<4) holds encoder unit-u state (r16=u, kk=0).
    float dc0 = 0.f, dc1 = 0.f;
    {
        float t0 = bperm(u << 2, c0);
        float t1 = bperm(u << 2, c1);
        if (u < 4) { dc0 = t0; dc1 = t1; }
    }
    float dh0[10], dh1[10];
#pragma unroll
    for (int j = 0; j < 10; ++j) {
        dh0[j] = (j < 4) ? h0v[j] : 0.f;
        dh1[j] = (j < 4) ? h1v[j] : 0.f;
    }

    float* __restrict__ noise_base = out + NOISE_OFF + b * T_N;
    float2* __restrict__ fin_base  = (float2*)out + b * T_N;

    float my_noise = 0.f;

    for (int t = 0; t < T_N; ++t) {
        const float inp = dh1[0];

        // L1 partial from previous h1 (independent of L0 chain); split chains
        float p0 = bb1, p1 = 0.f;
#pragma unroll
        for (int j = 0; j < 10; j += 2) {
            p0 = fmaf(whh1r[j], dh1[j], p0);
            p1 = fmaf(whh1r[j + 1], dh1[j + 1], p1);
        }
        const float pp = p0 + p1;

        // L0: this lane's gate row; split chains
        float a0 = fmaf(wih0, inp, bb0), a1 = 0.f;
#pragma unroll
        for (int j = 0; j < 10; j += 2) {
            a0 = fmaf(whh0r[j], dh0[j], a0);
            a1 = fmaf(whh0r[j + 1], dh0[j + 1], a1);
        }
        float gate = act_ab(a0 + a1, A1, B1);   // one exp2+rcp for all 40 rows
        float iv = bperm(a_i, gate);
        float fv = bperm(a_f, gate);
        float gv = bperm(a_g, gate);
        float ov = bperm(a_o, gate);
        dc0 = fmaf(fv, dc0, iv * gv);           // unit-u state, kept redundantly
        float h0u = ov * tanh_nat(dc0);
#pragma unroll
        for (int j = 0; j < 10; ++j) dh0[j] = bperm(j << 2, h0u);  // lane j = (k=0,u=j)

        // L1: this lane's gate row (post-broadcast half); split chains
        float q0 = 0.f, q1 = 0.f;
#pragma unroll
        for (int j = 0; j < 10; j += 2) {
            q0 = fmaf(wih1r[j], dh0[j], q0);
            q1 = fmaf(wih1r[j + 1], dh0[j + 1], q1);
        }
        float gate1 = act_ab(pp + q0 + q1, A1, B1);
        iv = bperm(a_i, gate1);
        fv = bperm(a_f, gate1);
        gv = bperm(a_g, gate1);
        ov = bperm(a_o, gate1);
        dc1 = fmaf(fv, dc1, iv * gv);
        float h1u = ov * tanh_nat(dc1);
#pragma unroll
        for (int j = 0; j < 10; ++j) dh1[j] = bperm(j << 2, h1u);

        // noise_t = dec_out . out_W + out_b (computed on every lane)
        float nz0 = outb0, nz1 = 0.f;
#pragma unroll
        for (int j = 0; j < 10; j += 2) {
            nz0 = fmaf(outw[j], dh1[j], nz0);
            nz1 = fmaf(outw[j + 1], dh1[j + 1], nz1);
        }
        const float nz = nz0 + nz1;

        // lane keeps t with t%64==wl; flush coalesced every 64 steps
        my_noise = ((t & 63) == wl) ? nz : my_noise;
        if ((t & 63) == 63) {
            const int off = (t - 63) + wl;
            noise_base[off] = my_noise;
            float2 fin;
            fin.x = my_noise + fw0;
            fin.y = my_noise + fw1;
            fin_base[off] = fin;
        }
    }
}

extern "C" void kernel_launch(void* const* d_in, const int* in_sizes, int n_in,
                              void* d_out, int out_size, void* d_ws, size_t ws_size,
                              hipStream_t stream) {
    const float* x     = (const float*)d_in[0];
    // d_in[1] = context (unused by the reference)
    const float* eWih0 = (const float*)d_in[2];
    const float* eWhh0 = (const float*)d_in[3];
    const float* ebih0 = (const float*)d_in[4];
    const float* ebhh0 = (const float*)d_in[5];
    const float* eWih1 = (const float*)d_in[6];
    const float* eWhh1 = (const float*)d_in[7];
    const float* ebih1 = (const float*)d_in[8];
    const float* ebhh1 = (const float*)d_in[9];
    const float* dWih0 = (const float*)d_in[10];
    const float* dWhh0 = (const float*)d_in[11];
    const float* dbih0 = (const float*)d_in[12];
    const float* dbhh0 = (const float*)d_in[13];
    const float* dWih1 = (const float*)d_in[14];
    const float* dWhh1 = (const float*)d_in[15];
    const float* dbih1 = (const float*)d_in[16];
    const float* dbhh1 = (const float*)d_in[17];
    const float* fcW   = (const float*)d_in[18];
    const float* fcb   = (const float*)d_in[19];
    const float* outW  = (const float*)d_in[20];
    const float* outb  = (const float*)d_in[21];

    float* out = (float*)d_out;

    // 4096 elems x 64 lanes = 262144 threads = 4096 waves = 4 waves/SIMD
    fused_kernel<<<dim3((B_N * 64) / 256), dim3(256), 0, stream>>>(
        x, eWih0, eWhh0, ebih0, ebhh0, eWih1, eWhh1, ebih1, ebhh1,
        dWih0, dWhh0, dbih0, dbhh0, dWih1, dWhh1, dbih1, dbhh1,
        fcW, fcb, outW, outb, out);
}